// Round 1
// baseline (1191.001 us; speedup 1.0000x reference)
//
#include <hip/hip_runtime.h>
#include <hip/hip_bf16.h>
#include <cstdint>

// Problem dims (fixed by the reference)
#define B_   8192
#define D_   1024
#define O_   1024
#define HE_  2048
#define NN_  7     // decision nodes
#define NL_  8     // leaves / experts
#define HR_  32    // router hidden
#define RC_  224   // NN_*HR_

typedef __attribute__((ext_vector_type(2))) float f32x2;
typedef __attribute__((ext_vector_type(4))) float f32x4;
typedef __attribute__((ext_vector_type(8))) short bf16x8;
typedef __attribute__((ext_vector_type(4))) unsigned short u16x4;
typedef unsigned short u16;
typedef unsigned int u32;

__device__ __forceinline__ u16 f2bf(float f) {
  __hip_bfloat16 h = __float2bfloat16(f);
  return *reinterpret_cast<u16*>(&h);
}
__device__ __forceinline__ float gelu_exact(float v) {
  return 0.5f * v * (1.0f + erff(v * 0.7071067811865475f));
}
__device__ __forceinline__ void gload16(const void* g, void* l) {
  __builtin_amdgcn_global_load_lds(
      (const __attribute__((address_space(1))) void*)(uintptr_t)g,
      (__attribute__((address_space(3))) void*)(uintptr_t)l,
      16, 0, 0);
}

// ---------------- f32 -> bf16 cast (x), 4 elems/thread, exact grid ----------
__global__ __launch_bounds__(256) void cvt_bf16_kernel(
    const float* __restrict__ in, u16* __restrict__ out) {
  size_t i = ((size_t)blockIdx.x * 256 + threadIdx.x) * 4;
  f32x4 f = *reinterpret_cast<const f32x4*>(in + i);
  u16x4 u;
  u[0] = f2bf(f[0]); u[1] = f2bf(f[1]); u[2] = f2bf(f[2]); u[3] = f2bf(f[3]);
  *reinterpret_cast<u16x4*>(out + i) = u;
}

// ------------- transpose + cvt: out[c*ldo + r] (+e*out_estride) = in[r][c] --
// 64x64 tiles, LDS pad 65 (2-way conflict = free per m136)
__global__ __launch_bounds__(256) void transpose_cvt_kernel(
    const float* __restrict__ in, u16* __restrict__ out,
    int R, int C, int ldo, long in_estride, long out_estride) {
  __shared__ __attribute__((aligned(16))) float tile[64][65];
  const float* in_e = in + (long)blockIdx.z * in_estride;
  u16* out_e = out + (long)blockIdx.z * out_estride;
  int t = threadIdx.x;
  int r0 = blockIdx.y * 64, c0 = blockIdx.x * 64;
  int cc = t & 63, rbase = t >> 6;
#pragma unroll
  for (int i = 0; i < 16; i++) {
    int rr = rbase + i * 4;
    tile[rr][cc] = in_e[(long)(r0 + rr) * C + c0 + cc];
  }
  __syncthreads();
  int r2 = (t & 31) * 2, cj = t >> 5;  // 0..7
#pragma unroll
  for (int i = 0; i < 8; i++) {
    int c = cj * 8 + i;
    u32 u = (u32)f2bf(tile[r2][c]) | ((u32)f2bf(tile[r2 + 1][c]) << 16);
    *reinterpret_cast<u32*>(out_e + (long)(c0 + c) * ldo + r0 + r2) = u;
  }
}

// ---------------- router layer 1: H1[b][224] = gelu(x @ rW1 + rb1), f32 -----
// 512 blocks x 128 thr; 16 rows/block; thread t<112 owns cols 2t,2t+1
__global__ __launch_bounds__(128) void router_h1_kernel(
    const float* __restrict__ x, const float* __restrict__ rW1,
    const float* __restrict__ rb1, float* __restrict__ H1) {
  __shared__ __attribute__((aligned(16))) float xs[64][20];  // [k][row], pad 20
  int t = threadIdx.x;
  int row0 = blockIdx.x * 16;
  float acc0[16], acc1[16];
#pragma unroll
  for (int i = 0; i < 16; i++) { acc0[i] = 0.f; acc1[i] = 0.f; }
  int node = t >> 4;
  int rcol = (2 * t) & 31;  // even col within node
  const float* wp = rW1 + (long)node * (D_ * HR_) + rcol;
  for (int k0 = 0; k0 < D_; k0 += 64) {
    __syncthreads();
#pragma unroll
    for (int i = 0; i < 8; i++) {
      int idx = t + i * 128;
      int rr = idx >> 6, kk = idx & 63;
      xs[kk][rr] = x[(long)(row0 + rr) * D_ + k0 + kk];
    }
    __syncthreads();
    if (t < 112) {
#pragma unroll 4
      for (int kk = 0; kk < 64; kk++) {
        f32x2 w = *reinterpret_cast<const f32x2*>(wp + (long)(k0 + kk) * HR_);
#pragma unroll
        for (int q = 0; q < 4; q++) {
          f32x4 xv = *reinterpret_cast<const f32x4*>(&xs[kk][q * 4]);
#pragma unroll
          for (int j = 0; j < 4; j++) {
            acc0[q * 4 + j] += xv[j] * w[0];
            acc1[q * 4 + j] += xv[j] * w[1];
          }
        }
      }
    }
  }
  if (t < 112) {
    float b0 = rb1[2 * t], b1 = rb1[2 * t + 1];
#pragma unroll
    for (int i = 0; i < 16; i++) {
      f32x2 g;
      g[0] = gelu_exact(acc0[i] + b0);
      g[1] = gelu_exact(acc1[i] + b1);
      *reinterpret_cast<f32x2*>(&H1[(long)(row0 + i) * RC_ + 2 * t]) = g;
    }
  }
}

// -------- router layer 2 + softmax + path products + top-k + renorm --------
__global__ __launch_bounds__(256) void router_logits_kernel(
    const float* __restrict__ H1, const float* __restrict__ rW2,
    const float* __restrict__ rb2, const int* __restrict__ topk_ptr,
    float* __restrict__ P) {
  int b = blockIdx.x * 256 + threadIdx.x;
  const float* hrow = H1 + (long)b * RC_;
  float dec[NN_][2];
#pragma unroll
  for (int n = 0; n < NN_; n++) {
    float l0 = rb2[n * 2], l1 = rb2[n * 2 + 1];
#pragma unroll
    for (int r4 = 0; r4 < HR_; r4 += 4) {
      f32x4 h = *reinterpret_cast<const f32x4*>(hrow + n * HR_ + r4);
#pragma unroll
      for (int j = 0; j < 4; j++) {
        l0 += h[j] * rW2[(n * HR_ + r4 + j) * 2];
        l1 += h[j] * rW2[(n * HR_ + r4 + j) * 2 + 1];
      }
    }
    float mx = fmaxf(l0, l1);
    float e0 = expf(l0 - mx), e1 = expf(l1 - mx);
    float s = e0 + e1;
    dec[n][0] = e0 / s; dec[n][1] = e1 / s;
  }
  float v[NL_];
#pragma unroll
  for (int L = 0; L < NL_; L++)
    v[L] = dec[0][L >> 2] * dec[1 + (L >> 2)][(L >> 1) & 1] * dec[3 + (L >> 1)][L & 1];
  int tk = *topk_ptr;
  float p[NL_];
  if (tk < NL_) {
    float s = 0.f;
    bool keep[NL_];
#pragma unroll
    for (int e = 0; e < NL_; e++) {
      int rank = 0;
#pragma unroll
      for (int j = 0; j < NL_; j++)
        rank += ((v[j] > v[e]) || (v[j] == v[e] && j < e)) ? 1 : 0;
      keep[e] = rank < tk;
      if (keep[e]) s += v[e];
    }
    float inv = 1.f / (s + 1e-8f);
#pragma unroll
    for (int e = 0; e < NL_; e++) p[e] = keep[e] ? v[e] * inv : 0.f;
  } else {
#pragma unroll
    for (int e = 0; e < NL_; e++) p[e] = v[e];
  }
#pragma unroll
  for (int e = 0; e < NL_; e++) P[(long)b * NL_ + e] = p[e];
}

// ---------------- GEMM1: H = p_e * gelu(Xb @ W1t^T + eb1), bf16 out --------
// m97 structure: 128x128 tile, BK=32, 4 waves (2x2), 16x16x32 bf16 MFMA,
// global_load_lds width-16 staging, band map (GROUP=8) + XCD swizzle.
__global__ __launch_bounds__(256, 2) void gemm1_kernel(
    const u16* __restrict__ A, const u16* __restrict__ Bm,
    const float* __restrict__ eb1, const float* __restrict__ P,
    u16* __restrict__ H, int K, int lda, int ldb, int ldh,
    int ncol_off, int tiles_n) {
  __shared__ __attribute__((aligned(16))) u16 lA[128 * 32];
  __shared__ __attribute__((aligned(16))) u16 lB[128 * 32];
  int tid = threadIdx.x;
  int gid = blockIdx.x;
  int cpx = gridDim.x >> 3;
  gid = (gid & 7) * cpx + (gid >> 3);          // XCD-contiguous (bijective)
  int bandsz = tiles_n * 8;
  int band = gid / bandsz, inb = gid % bandsz;
  long m0 = (long)(band * 8 + (inb & 7)) * 128;
  long n0 = (long)(inb >> 3) * 128;
  int wid = tid >> 6, lane = tid & 63;
  int wm = wid >> 1, wn = wid & 1;
  f32x4 acc[4][4];
#pragma unroll
  for (int m = 0; m < 4; m++)
#pragma unroll
    for (int n = 0; n < 4; n++) acc[m][n] = (f32x4){0.f, 0.f, 0.f, 0.f};
  int lr = lane & 15, lk = (lane >> 4) * 8;
  int srow = tid >> 2, soff = (tid & 3) * 8;
  const u16* Ab = A + m0 * lda;
  const u16* Bb = Bm + n0 * ldb;
  for (int k0 = 0; k0 < K; k0 += 32) {
    gload16(Ab + (long)srow * lda + k0 + soff, &lA[tid * 8]);
    gload16(Ab + (long)(64 + srow) * lda + k0 + soff, &lA[(256 + tid) * 8]);
    gload16(Bb + (long)srow * ldb + k0 + soff, &lB[tid * 8]);
    gload16(Bb + (long)(64 + srow) * ldb + k0 + soff, &lB[(256 + tid) * 8]);
    __syncthreads();
    bf16x8 af[4], bfr[4];
#pragma unroll
    for (int m = 0; m < 4; m++)
      af[m] = *reinterpret_cast<const bf16x8*>(&lA[(wm * 64 + m * 16 + lr) * 32 + lk]);
#pragma unroll
    for (int n = 0; n < 4; n++)
      bfr[n] = *reinterpret_cast<const bf16x8*>(&lB[(wn * 64 + n * 16 + lr) * 32 + lk]);
#pragma unroll
    for (int m = 0; m < 4; m++)
#pragma unroll
      for (int n = 0; n < 4; n++)
        acc[m][n] = __builtin_amdgcn_mfma_f32_16x16x32_bf16(af[m], bfr[n], acc[m][n], 0, 0, 0);
    __syncthreads();
  }
  int lq = lane >> 4;
#pragma unroll
  for (int m = 0; m < 4; m++)
#pragma unroll
    for (int n = 0; n < 4; n++)
#pragma unroll
      for (int j = 0; j < 4; j++) {
        long row = m0 + wm * 64 + m * 16 + lq * 4 + j;
        long col = n0 + wn * 64 + n * 16 + lr;
        int colT = (int)col + ncol_off;
        float vv = gelu_exact(acc[m][n][j] + eb1[colT]);
        float pw = P[row * NL_ + (colT >> 11)];   // expert = colT / HE_
        H[row * ldh + col] = f2bf(vv * pw);
      }
}

// ---------------- GEMM2: Y = Hcat @ W2t^T + sum_e p_e*eb2_e ----------------
__global__ __launch_bounds__(256, 2) void gemm2_kernel(
    const u16* __restrict__ A, const u16* __restrict__ Bm,
    const float* __restrict__ eb2, const float* __restrict__ P,
    float* __restrict__ Y, int K, int lda, int ldb,
    int tiles_n, int expert, int first) {
  __shared__ __attribute__((aligned(16))) u16 lA[128 * 32];
  __shared__ __attribute__((aligned(16))) u16 lB[128 * 32];
  int tid = threadIdx.x;
  int gid = blockIdx.x;
  int cpx = gridDim.x >> 3;
  gid = (gid & 7) * cpx + (gid >> 3);
  int bandsz = tiles_n * 8;
  int band = gid / bandsz, inb = gid % bandsz;
  long m0 = (long)(band * 8 + (inb & 7)) * 128;
  long n0 = (long)(inb >> 3) * 128;
  int wid = tid >> 6, lane = tid & 63;
  int wm = wid >> 1, wn = wid & 1;
  f32x4 acc[4][4];
#pragma unroll
  for (int m = 0; m < 4; m++)
#pragma unroll
    for (int n = 0; n < 4; n++) acc[m][n] = (f32x4){0.f, 0.f, 0.f, 0.f};
  int lr = lane & 15, lk = (lane >> 4) * 8;
  int srow = tid >> 2, soff = (tid & 3) * 8;
  const u16* Ab = A + m0 * lda;
  const u16* Bb = Bm + n0 * ldb;
  for (int k0 = 0; k0 < K; k0 += 32) {
    gload16(Ab + (long)srow * lda + k0 + soff, &lA[tid * 8]);
    gload16(Ab + (long)(64 + srow) * lda + k0 + soff, &lA[(256 + tid) * 8]);
    gload16(Bb + (long)srow * ldb + k0 + soff, &lB[tid * 8]);
    gload16(Bb + (long)(64 + srow) * ldb + k0 + soff, &lB[(256 + tid) * 8]);
    __syncthreads();
    bf16x8 af[4], bfr[4];
#pragma unroll
    for (int m = 0; m < 4; m++)
      af[m] = *reinterpret_cast<const bf16x8*>(&lA[(wm * 64 + m * 16 + lr) * 32 + lk]);
#pragma unroll
    for (int n = 0; n < 4; n++)
      bfr[n] = *reinterpret_cast<const bf16x8*>(&lB[(wn * 64 + n * 16 + lr) * 32 + lk]);
#pragma unroll
    for (int m = 0; m < 4; m++)
#pragma unroll
      for (int n = 0; n < 4; n++)
        acc[m][n] = __builtin_amdgcn_mfma_f32_16x16x32_bf16(af[m], bfr[n], acc[m][n], 0, 0, 0);
    __syncthreads();
  }
  int lq = lane >> 4;
#pragma unroll
  for (int m = 0; m < 4; m++)
#pragma unroll
    for (int n = 0; n < 4; n++)
#pragma unroll
      for (int j = 0; j < 4; j++) {
        long row = m0 + wm * 64 + m * 16 + lq * 4 + j;
        long col = n0 + wn * 64 + n * 16 + lr;
        float vv = acc[m][n][j];
        if (expert < 0) {
          float bsum = 0.f;
#pragma unroll
          for (int e = 0; e < NL_; e++) bsum += P[row * NL_ + e] * eb2[e * O_ + col];
          Y[row * O_ + col] = vv + bsum;
        } else {
          vv += P[row * NL_ + expert] * eb2[expert * O_ + col];
          if (first) Y[row * O_ + col] = vv;
          else       Y[row * O_ + col] += vv;
        }
      }
}

extern "C" void kernel_launch(void* const* d_in, const int* in_sizes, int n_in,
                              void* d_out, int out_size, void* d_ws, size_t ws_size,
                              hipStream_t stream) {
  (void)in_sizes; (void)n_in; (void)out_size;
  const float* x   = (const float*)d_in[0];
  const float* rW1 = (const float*)d_in[1];
  const float* rb1 = (const float*)d_in[2];
  const float* rW2 = (const float*)d_in[3];
  const float* rb2 = (const float*)d_in[4];
  const float* eW1 = (const float*)d_in[5];
  const float* eb1 = (const float*)d_in[6];
  const float* eW2 = (const float*)d_in[7];
  const float* eb2 = (const float*)d_in[8];
  const int*  topk = (const int*)d_in[9];
  float* y = (float*)d_out;
  float* P = y + (size_t)B_ * O_;   // leaf_probs live in d_out tail

  char* ws = (char*)d_ws;
  size_t off = 0;
  auto take = [&](size_t bytes) {
    size_t o = off; off += (bytes + 255) & ~(size_t)255; return o;
  };
  u16*  Xb  = (u16*)(ws + take((size_t)B_ * D_ * 2));
  u16*  W1t = (u16*)(ws + take((size_t)NL_ * HE_ * D_ * 2));   // [16384][1024]
  u16*  W2t = (u16*)(ws + take((size_t)O_ * NL_ * HE_ * 2));   // [1024][16384]
  float* H1 = (float*)(ws + take((size_t)B_ * RC_ * 4));
  size_t base = off;
  bool fused = (base + (size_t)B_ * NL_ * HE_ * 2) <= ws_size;  // Hcat 268 MB
  u16* Hbuf = (u16*)(ws + base);

  cvt_bf16_kernel<<<(B_ * D_) / 1024, 256, 0, stream>>>(x, Xb);
  // W1t[e*HE+n][k] = eW1[e][k][n]
  transpose_cvt_kernel<<<dim3(HE_ / 64, D_ / 64, NL_), 256, 0, stream>>>(
      eW1, W1t, D_, HE_, D_, (long)D_ * HE_, (long)HE_ * D_);
  // W2t[o][e*HE+h] = eW2[e][h][o]
  transpose_cvt_kernel<<<dim3(O_ / 64, HE_ / 64, NL_), 256, 0, stream>>>(
      eW2, W2t, HE_, O_, NL_ * HE_, (long)HE_ * O_, (long)HE_);
  router_h1_kernel<<<B_ / 16, 128, 0, stream>>>(x, rW1, rb1, H1);
  router_logits_kernel<<<B_ / 256, 256, 0, stream>>>(H1, rW2, rb2, topk, P);

  if (fused) {
    gemm1_kernel<<<64 * (NL_ * HE_ / 128), 256, 0, stream>>>(
        Xb, W1t, eb1, P, Hbuf, D_, D_, D_, NL_ * HE_, 0, NL_ * HE_ / 128);
    gemm2_kernel<<<64 * (O_ / 128), 256, 0, stream>>>(
        Hbuf, W2t, eb2, P, y, NL_ * HE_, NL_ * HE_, NL_ * HE_, O_ / 128, -1, 1);
  } else {
    for (int e = 0; e < NL_; e++) {
      gemm1_kernel<<<64 * (HE_ / 128), 256, 0, stream>>>(
          Xb, W1t + (size_t)e * HE_ * D_, eb1, P, Hbuf, D_, D_, D_, HE_,
          e * HE_, HE_ / 128);
      gemm2_kernel<<<64 * (O_ / 128), 256, 0, stream>>>(
          Hbuf, W2t + (size_t)e * HE_, eb2, P, y, HE_, HE_, NL_ * HE_,
          O_ / 128, e, e == 0);
    }
  }
}